// Round 23
// baseline (193.552 us; speedup 1.0000x reference)
//
#include <hip/hip_runtime.h>
#include <hip/hip_bf16.h>
#include <stdint.h>

// ---------------- problem geometry ----------------
constexpr int L  = 2048;
constexpr int NB = 4;                 // batch
constexpr int E  = 1024;
constexpr int H  = 16;
constexpr int M  = L * NB;            // 8192 tokens
constexpr int K  = E;                 // 1024 (GEMM inner dim)
constexpr int QKV_LD = 3 * E;         // 3072

typedef float  f32x4  __attribute__((ext_vector_type(4)));
typedef float  f32x16 __attribute__((ext_vector_type(16)));
typedef __bf16 bf16x4 __attribute__((ext_vector_type(4)));
typedef __bf16 bf16x8 __attribute__((ext_vector_type(8)));
typedef unsigned int uint2v __attribute__((ext_vector_type(2)));
typedef unsigned int uint4v __attribute__((ext_vector_type(4)));

#define AS1 __attribute__((address_space(1)))
#define AS3 __attribute__((address_space(3)))

static __device__ __forceinline__ void gl_lds16(const void* g, void* l) {
  __builtin_amdgcn_global_load_lds((const AS1 uint32_t*)g, (AS3 uint32_t*)l, 16, 0, 0);
}

// =====================================================================
// fp32 -> bf16 bulk convert, all three tensors in ONE launch.
// =====================================================================
__global__ __launch_bounds__(256)
void cvt_all(const float* __restrict__ x, const float* __restrict__ wq,
             const float* __restrict__ wo, __bf16* __restrict__ xb,
             __bf16* __restrict__ wqb, __bf16* __restrict__ wob) {
  const int bid = blockIdx.x;
  const float* src;
  __bf16* dst;
  int i;
  if (bid < 8192)        { src = x;  dst = xb;  i = bid * 256 + threadIdx.x; }
  else if (bid < 11264)  { src = wq; dst = wqb; i = (bid - 8192) * 256 + threadIdx.x; }
  else                   { src = wo; dst = wob; i = (bid - 11264) * 256 + threadIdx.x; }
  const f32x4 v = ((const f32x4*)src)[i];
  bf16x4 o;
#pragma unroll
  for (int j = 0; j < 4; j++) o[j] = (__bf16)v[j];
  ((bf16x4*)dst)[i] = o;
}

// =====================================================================
// GEMM: C[M][NC] = A[M][K] * B[NC][K]^T  (bf16 in, fp32 accum, OutT out)
// T1 bijective XCD swizzle. (validated r9/r12/r15)
// =====================================================================
template<int NC, typename OutT>
__global__ __launch_bounds__(256)
void gemm_bt(const __bf16* __restrict__ A, const __bf16* __restrict__ B,
             OutT* __restrict__ C) {
  constexpr int BK = 64;
  __shared__ char lds[2 * 128 * BK * 2];
  char* aL = lds;
  char* bL = lds + 128 * BK * 2;

  const int t    = threadIdx.x;
  const int lane = t & 63;
  const int w    = t >> 6;
  const int g    = lane >> 4;
  const int c    = lane & 15;

  const int nwg = gridDim.x * gridDim.y;
  const int lin = blockIdx.x + gridDim.x * blockIdx.y;
  const int q8  = nwg >> 3;
  const int swz = (lin & 7) * q8 + (lin >> 3);
  const int bx  = swz % gridDim.x;
  const int by  = swz / gridDim.x;

  const int rowBase = by * 128;
  const int colBase = bx * 128;

  const int srow = t >> 3;
  const int scb  = (t & 7) * 16;
  const int ssw  = scb ^ ((srow & 7) << 4);

  const char* aSrcBase = (const char*)(A + (size_t)(rowBase + srow) * K) + ssw;
  const char* bSrcBase = (const char*)(B + (size_t)(colBase + srow) * K) + ssw;

  f32x4 acc[4][4];
#pragma unroll
  for (int i = 0; i < 4; i++)
#pragma unroll
    for (int j = 0; j < 4; j++) acc[i][j] = f32x4{0.f, 0.f, 0.f, 0.f};

  const int wr = (w >> 1) * 64;
  const int wc = (w & 1) * 64;

  for (int k0 = 0; k0 < K; k0 += BK) {
    __syncthreads();
#pragma unroll
    for (int q = 0; q < 4; q++) {
      gl_lds16(aSrcBase + (size_t)2 * k0 + (size_t)q * 32 * K * 2, aL + q * 4096 + t * 16);
      gl_lds16(bSrcBase + (size_t)2 * k0 + (size_t)q * 32 * K * 2, bL + q * 4096 + t * 16);
    }
    __syncthreads();

    bf16x8 af[4][2], bfR[4][2];
#pragma unroll
    for (int mi = 0; mi < 4; mi++) {
      const int row = wr + mi * 16 + c;
      const int sw  = (row & 7) << 4;
#pragma unroll
      for (int ks = 0; ks < 2; ks++)
        af[mi][ks] = *(const bf16x8*)(aL + row * 128 + ((ks * 64 + g * 16) ^ sw));
    }
#pragma unroll
    for (int ni = 0; ni < 4; ni++) {
      const int row = wc + ni * 16 + c;
      const int sw  = (row & 7) << 4;
#pragma unroll
      for (int ks = 0; ks < 2; ks++)
        bfR[ni][ks] = *(const bf16x8*)(bL + row * 128 + ((ks * 64 + g * 16) ^ sw));
    }
#pragma unroll
    for (int mi = 0; mi < 4; mi++)
#pragma unroll
      for (int ni = 0; ni < 4; ni++)
#pragma unroll
        for (int ks = 0; ks < 2; ks++)
          acc[mi][ni] = __builtin_amdgcn_mfma_f32_16x16x32_bf16(
              af[mi][ks], bfR[ni][ks], acc[mi][ni], 0, 0, 0);
  }

#pragma unroll
  for (int mi = 0; mi < 4; mi++)
#pragma unroll
    for (int ni = 0; ni < 4; ni++)
#pragma unroll
      for (int r = 0; r < 4; r++) {
        const int row = rowBase + wr + mi * 16 + g * 4 + r;
        const int col = colBase + wc + ni * 16 + c;
        C[(size_t)row * NC + col] = (OutT)acc[mi][ni][r];
      }
}

// =====================================================================
// V transpose: qkv V-section [l][n][h*64+d] -> vT[(n*16+h)*64+d][l]
// =====================================================================
__global__ __launch_bounds__(256)
void transpose_v(const __bf16* __restrict__ qkv, __bf16* __restrict__ vT) {
  __shared__ char tile[64 * 160];
  const int lt = blockIdx.x;
  const int bh = blockIdx.y;
  const int n  = bh >> 4, h = bh & 15;
  const int t  = threadIdx.x;
  const int r8 = t >> 3;
  const int c8 = (t & 7) * 8;

#pragma unroll
  for (int q2 = 0; q2 < 2; q2++) {
    const int l = q2 * 32 + r8;
    const bf16x8 v = *(const bf16x8*)(qkv + (size_t)((lt * 64 + l) * 4 + n) * QKV_LD +
                                      2 * E + h * 64 + c8);
    *(bf16x8*)(tile + l * 160 + ((c8 * 2) ^ (((l >> 3) & 7) << 4))) = v;
  }
  __syncthreads();
#pragma unroll
  for (int q2 = 0; q2 < 2; q2++) {
    const int d = q2 * 32 + r8;
    bf16x8 o;
#pragma unroll
    for (int i = 0; i < 8; i++) {
      const int l = c8 + i;
      o[i] = *(const __bf16*)(tile + l * 160 + ((d * 2) ^ (((l >> 3) & 7) << 4)));
    }
    *(bf16x8*)(vT + ((size_t)bh * 64 + d) * 2048 + lt * 64 + c8) = o;
  }
}

// =====================================================================
// Causal flash attention, oversubscribed small blocks + dbuf staging.
// grid (64, 32), 128 threads (2 waves): block (b, y) owns the 64-q
// supertile sup = 31-y. r22 structure with DOUBLE-BUFFERED K/V
// (32 KB LDS, 5 blocks/CU cap): per iteration the vmcnt drain lands
// after a full compute phase (r15-validated prefetch pattern), removing
// the serial stage-drain from the per-iteration critical path.
// Per-wave compute body: r12-validated core (swapped QK^T 32x32x16,
// lane-local defer-max softmax, in-reg P, shfl_xor(32) PV exchange).
// =====================================================================
__global__ __launch_bounds__(128)
void attn_kernel(const __bf16* __restrict__ qkv, const __bf16* __restrict__ vT,
                 __bf16* __restrict__ out) {
  const int b   = blockIdx.x;           // 0..63 (n*16+h); XCD = b%8 L2 locality
  const int sup = 31 - (int)blockIdx.y; // 64-q supertile, longest first
  const int n   = b >> 4;
  const int h   = b & 15;

  __shared__ char kl[2][64 * 128];    // K tiles [kv64][d64], sw2-swizzled
  __shared__ char vl[2][64 * 128];    // V^T tiles [d64][kv64], sw2-swizzled

  const int t    = threadIdx.x;       // 0..127
  const int lane = t & 63;
  const int w    = t >> 6;            // 0..1
  const int l31  = lane & 31;
  const int hi   = lane >> 5;

  // staging: 4 chunks of 16 rows x 128B (8 thr/row); linear LDS dest,
  // pre-swizzled global source (both-sides rule)
  const int srow = t >> 3;            // 0..15
  const int scb  = (t & 7) * 16;
  int kssw[4];
#pragma unroll
  for (int q2 = 0; q2 < 4; q2++) {
    const int row = q2 * 16 + srow;
    kssw[q2] = scb ^ (((row ^ (row >> 3)) & 7) << 4);
  }

  // fragment-read rows (fixed per lane): rows l31 and 32+l31
  const int krow0 = l31,      sw0 = ((krow0 ^ (krow0 >> 3)) & 7) << 4;
  const int krow1 = 32 + l31, sw1 = ((krow1 ^ (krow1 >> 3)) & 7) << 4;

  constexpr float QSCALE = 0.125f * 1.4426950408889634f;

  const int qb_ = sup * 64 + w * 32;  // wave's q-base
  const int qg  = qb_ + l31;          // lane's global q row

  // Q as B-fragments: col q = l31, k = d = ds*16 + hi*8 + i
  bf16x8 qb[4];
  {
    const __bf16* qp = qkv + (size_t)(qg * 4 + n) * QKV_LD + h * 64;
#pragma unroll
    for (int ds = 0; ds < 4; ds++) {
      qb[ds] = *(const bf16x8*)(qp + ds * 16 + hi * 8);
#pragma unroll
      for (int i = 0; i < 8; i++) qb[ds][i] = (__bf16)((float)qb[ds][i] * QSCALE);
    }
  }

  float m_c = -3e38f, l_c = 0.f;
  f32x16 o0, o1;                      // O[q32][d32] frags, d-halves
#pragma unroll
  for (int j = 0; j < 16; j++) { o0[j] = 0.f; o1[j] = 0.f; }

  int cur = 0;

  // prologue: stage kv-tile 0 into buf 0
#pragma unroll
  for (int q2 = 0; q2 < 4; q2++) {
    const int kvrow = q2 * 16 + srow;
    gl_lds16((const char*)(qkv + (size_t)(kvrow * 4 + n) * QKV_LD + E + h * 64) + kssw[q2],
             kl[0] + q2 * 2048 + t * 16);
    gl_lds16((const char*)(vT + ((size_t)b * 64 + q2 * 16 + srow) * 2048) + kssw[q2],
             vl[0] + q2 * 2048 + t * 16);
  }

  for (int kt = 0; kt <= sup; ++kt) {
    __syncthreads();                  // drains vmcnt -> buf[cur] ready

    // ---- issue prefetch of tile kt+1 into buf[cur^1] ----
    if (kt < sup) {
      const int nx = kt + 1;
#pragma unroll
      for (int q2 = 0; q2 < 4; q2++) {
        const int kvrow = nx * 64 + q2 * 16 + srow;
        gl_lds16((const char*)(qkv + (size_t)(kvrow * 4 + n) * QKV_LD + E + h * 64) + kssw[q2],
                 kl[cur ^ 1] + q2 * 2048 + t * 16);
        const int vd = q2 * 16 + srow;
        gl_lds16((const char*)(vT + ((size_t)b * 64 + vd) * 2048 + nx * 64) + kssw[q2],
                 vl[cur ^ 1] + q2 * 2048 + t * 16);
      }
    }
    __builtin_amdgcn_sched_barrier(0);   // pin issue-early order

    const char* klc = kl[cur];
    const char* vlc = vl[cur];

    // ---- S^T[kv64][q32]: two 32x32 frags (kv-halves) ----
    f32x16 s0, s1;
#pragma unroll
    for (int j = 0; j < 16; j++) { s0[j] = 0.f; s1[j] = 0.f; }
    __builtin_amdgcn_s_setprio(1);
#pragma unroll
    for (int ds = 0; ds < 4; ds++) {
      const int col = ds * 32 + hi * 16;
      const bf16x8 ka0 = *(const bf16x8*)(klc + krow0 * 128 + (col ^ sw0));
      const bf16x8 ka1 = *(const bf16x8*)(klc + krow1 * 128 + (col ^ sw1));
      s0 = __builtin_amdgcn_mfma_f32_32x32x16_bf16(ka0, qb[ds], s0, 0, 0, 0);
      s1 = __builtin_amdgcn_mfma_f32_32x32x16_bf16(ka1, qb[ds], s1, 0, 0, 0);
    }
    __builtin_amdgcn_s_setprio(0);

    // ---- causal mask: diagonal tile only (kt == sup) ----
    if (kt == sup) {
#pragma unroll
      for (int reg = 0; reg < 16; reg++) {
        const int kvp = (reg & 3) + 8 * (reg >> 2) + 4 * hi;
        if (kt * 64 + kvp      > qg) s0[reg] = -1e30f;
        if (kt * 64 + 32 + kvp > qg) s1[reg] = -1e30f;
      }
    }

    // ---- lane-local online softmax (q = l31), T13 defer-max ----
    float rmax = s0[0];
#pragma unroll
    for (int reg = 1; reg < 16; reg++) rmax = fmaxf(rmax, s0[reg]);
#pragma unroll
    for (int reg = 0; reg < 16; reg++) rmax = fmaxf(rmax, s1[reg]);
    rmax = fmaxf(rmax, __shfl_xor(rmax, 32));

    if (__any(rmax > m_c + 8.f)) {
      const float mnew  = fmaxf(m_c, rmax);
      const float alpha = exp2f(m_c - mnew);
      l_c *= alpha;
#pragma unroll
      for (int reg = 0; reg < 16; reg++) {
        const int   qp = (reg & 3) + 8 * (reg >> 2) + 4 * hi;
        const float ar = __shfl(alpha, qp);
        o0[reg] *= ar;
        o1[reg] *= ar;
      }
      m_c = mnew;
    }

    float rsum = 0.f;
#pragma unroll
    for (int reg = 0; reg < 16; reg++) {
      const float e0 = exp2f(s0[reg] - m_c);
      const float e1 = exp2f(s1[reg] - m_c);
      s0[reg] = e0; s1[reg] = e1;
      rsum += e0 + e1;
    }
    rsum += __shfl_xor(rsum, 32);
    l_c += rsum;

    // ---- pack P runs: run[rg] = 4 bf16 at kv = 8*rg' + 4*hi + {0..3}
    //      (+32 for rg>=4); dwords kept split for the exchange ----
    unsigned int runA[8], runB[8];
#pragma unroll
    for (int rg = 0; rg < 8; rg++) {
      bf16x4 pk;
#pragma unroll
      for (int j = 0; j < 4; j++)
        pk[j] = (__bf16)((rg < 4) ? s0[(rg & 3) * 4 + j] : s1[(rg & 3) * 4 + j]);
      const uint2v u = *(const uint2v*)&pk;
      runA[rg] = u[0]; runB[rg] = u[1];
    }

    // ---- PV: A-frag P[q=l31][kv=16s+8hi+0..7] via hi-half exchange ----
#pragma unroll
    for (int s_ = 0; s_ < 4; s_++) {
      const unsigned int ownA = hi ? runA[2 * s_ + 1] : runA[2 * s_];
      const unsigned int ownB = hi ? runB[2 * s_ + 1] : runB[2 * s_];
      const unsigned int sndA = hi ? runA[2 * s_]     : runA[2 * s_ + 1];
      const unsigned int sndB = hi ? runB[2 * s_]     : runB[2 * s_ + 1];
      const unsigned int rxA  = (unsigned int)__shfl_xor((int)sndA, 32);
      const unsigned int rxB  = (unsigned int)__shfl_xor((int)sndB, 32);
      uint4v pu;
      pu[0] = hi ? rxA : ownA;  pu[1] = hi ? rxB : ownB;
      pu[2] = hi ? ownA : rxA;  pu[3] = hi ? ownB : rxB;
      const bf16x8 pa = *(const bf16x8*)&pu;

      const int colp = s_ * 32 + hi * 16;
      const bf16x8 vb0 = *(const bf16x8*)(vlc + krow0 * 128 + (colp ^ sw0));
      const bf16x8 vb1 = *(const bf16x8*)(vlc + krow1 * 128 + (colp ^ sw1));
      __builtin_amdgcn_s_setprio(1);
      o0 = __builtin_amdgcn_mfma_f32_32x32x16_bf16(pa, vb0, o0, 0, 0, 0);
      o1 = __builtin_amdgcn_mfma_f32_32x32x16_bf16(pa, vb1, o1, 0, 0, 0);
      __builtin_amdgcn_s_setprio(0);
    }

    cur ^= 1;
  }

  // ---- epilogue: O row q = (reg&3)+8*(reg>>2)+4*hi, col d = dh*32+l31 ----
  const float inv = 1.f / l_c;
#pragma unroll
  for (int reg = 0; reg < 16; reg++) {
    const int   qp  = (reg & 3) + 8 * (reg >> 2) + 4 * hi;
    const float li  = __shfl(inv, qp);
    const int   qrw = qb_ + qp;
    const size_t base = (size_t)(qrw * 4 + n) * E + h * 64;
    out[base + l31]      = (__bf16)(o0[reg] * li);
    out[base + 32 + l31] = (__bf16)(o1[reg] * li);
  }
}

// =====================================================================
extern "C" void kernel_launch(void* const* d_in, const int* in_sizes, int n_in,
                              void* d_out, int out_size, void* d_ws, size_t ws_size,
                              hipStream_t stream) {
  const float* x    = (const float*)d_in[0];
  const float* wqkv = (const float*)d_in[1];
  const float* wout = (const float*)d_in[2];

  char* ws = (char*)d_ws;
  __bf16* x_bf    = (__bf16*)ws;                         ws += (size_t)M * E * 2;       // 16 MB
  __bf16* wqkv_bf = (__bf16*)ws;                         ws += (size_t)QKV_LD * E * 2;  //  6 MB
  __bf16* wout_bf = (__bf16*)ws;                         ws += (size_t)E * E * 2;       //  2 MB
  __bf16* qkv     = (__bf16*)ws;                         ws += (size_t)M * QKV_LD * 2;  // 48 MB
  __bf16* attno   = (__bf16*)ws;                                                        // 16 MB
  __bf16* vT      = x_bf;   // x_bf dead after QKV GEMM; reuse as vT (16 MB)
  float*  outp    = (float*)d_out;

  cvt_all<<<12288, 256, 0, stream>>>(x, wqkv, wout, x_bf, wqkv_bf, wout_bf);

  gemm_bt<QKV_LD, __bf16><<<dim3(QKV_LD / 128, M / 128), 256, 0, stream>>>(x_bf, wqkv_bf, qkv);
  transpose_v<<<dim3(L / 64, NB * H), 256, 0, stream>>>(qkv, vT);
  attn_kernel<<<dim3(NB * H, 32), 128, 0, stream>>>(qkv, vT, attno);
  gemm_bt<E, float><<<dim3(E / 128, M / 128), 256, 0, stream>>>(attno, wout_bf, outp);
}

// Round 24
// 192.488 us; speedup vs baseline: 1.0055x; 1.0055x over previous
//
#include <hip/hip_runtime.h>
#include <hip/hip_bf16.h>
#include <stdint.h>

// ---------------- problem geometry ----------------
constexpr int L  = 2048;
constexpr int NB = 4;                 // batch
constexpr int E  = 1024;
constexpr int H  = 16;
constexpr int M  = L * NB;            // 8192 tokens
constexpr int K  = E;                 // 1024 (GEMM inner dim)
constexpr int QKV_LD = 3 * E;         // 3072

typedef float  f32x4  __attribute__((ext_vector_type(4)));
typedef float  f32x16 __attribute__((ext_vector_type(16)));
typedef __bf16 bf16x4 __attribute__((ext_vector_type(4)));
typedef __bf16 bf16x8 __attribute__((ext_vector_type(8)));
typedef unsigned int uint2v __attribute__((ext_vector_type(2)));
typedef unsigned int uint4v __attribute__((ext_vector_type(4)));

#define AS1 __attribute__((address_space(1)))
#define AS3 __attribute__((address_space(3)))

static __device__ __forceinline__ void gl_lds16(const void* g, void* l) {
  __builtin_amdgcn_global_load_lds((const AS1 uint32_t*)g, (AS3 uint32_t*)l, 16, 0, 0);
}

// =====================================================================
// fp32 -> bf16 bulk convert, all three tensors in ONE launch.
// =====================================================================
__global__ __launch_bounds__(256)
void cvt_all(const float* __restrict__ x, const float* __restrict__ wq,
             const float* __restrict__ wo, __bf16* __restrict__ xb,
             __bf16* __restrict__ wqb, __bf16* __restrict__ wob) {
  const int bid = blockIdx.x;
  const float* src;
  __bf16* dst;
  int i;
  if (bid < 8192)        { src = x;  dst = xb;  i = bid * 256 + threadIdx.x; }
  else if (bid < 11264)  { src = wq; dst = wqb; i = (bid - 8192) * 256 + threadIdx.x; }
  else                   { src = wo; dst = wob; i = (bid - 11264) * 256 + threadIdx.x; }
  const f32x4 v = ((const f32x4*)src)[i];
  bf16x4 o;
#pragma unroll
  for (int j = 0; j < 4; j++) o[j] = (__bf16)v[j];
  ((bf16x4*)dst)[i] = o;
}

// =====================================================================
// GEMM: C[M][NC] = A[M][K] * B[NC][K]^T  (bf16 in, fp32 accum, OutT out)
// T1 bijective XCD swizzle. (validated r9/r12/r15)
// =====================================================================
template<int NC, typename OutT>
__global__ __launch_bounds__(256)
void gemm_bt(const __bf16* __restrict__ A, const __bf16* __restrict__ B,
             OutT* __restrict__ C) {
  constexpr int BK = 64;
  __shared__ char lds[2 * 128 * BK * 2];
  char* aL = lds;
  char* bL = lds + 128 * BK * 2;

  const int t    = threadIdx.x;
  const int lane = t & 63;
  const int w    = t >> 6;
  const int g    = lane >> 4;
  const int c    = lane & 15;

  const int nwg = gridDim.x * gridDim.y;
  const int lin = blockIdx.x + gridDim.x * blockIdx.y;
  const int q8  = nwg >> 3;
  const int swz = (lin & 7) * q8 + (lin >> 3);
  const int bx  = swz % gridDim.x;
  const int by  = swz / gridDim.x;

  const int rowBase = by * 128;
  const int colBase = bx * 128;

  const int srow = t >> 3;
  const int scb  = (t & 7) * 16;
  const int ssw  = scb ^ ((srow & 7) << 4);

  const char* aSrcBase = (const char*)(A + (size_t)(rowBase + srow) * K) + ssw;
  const char* bSrcBase = (const char*)(B + (size_t)(colBase + srow) * K) + ssw;

  f32x4 acc[4][4];
#pragma unroll
  for (int i = 0; i < 4; i++)
#pragma unroll
    for (int j = 0; j < 4; j++) acc[i][j] = f32x4{0.f, 0.f, 0.f, 0.f};

  const int wr = (w >> 1) * 64;
  const int wc = (w & 1) * 64;

  for (int k0 = 0; k0 < K; k0 += BK) {
    __syncthreads();
#pragma unroll
    for (int q = 0; q < 4; q++) {
      gl_lds16(aSrcBase + (size_t)2 * k0 + (size_t)q * 32 * K * 2, aL + q * 4096 + t * 16);
      gl_lds16(bSrcBase + (size_t)2 * k0 + (size_t)q * 32 * K * 2, bL + q * 4096 + t * 16);
    }
    __syncthreads();

    bf16x8 af[4][2], bfR[4][2];
#pragma unroll
    for (int mi = 0; mi < 4; mi++) {
      const int row = wr + mi * 16 + c;
      const int sw  = (row & 7) << 4;
#pragma unroll
      for (int ks = 0; ks < 2; ks++)
        af[mi][ks] = *(const bf16x8*)(aL + row * 128 + ((ks * 64 + g * 16) ^ sw));
    }
#pragma unroll
    for (int ni = 0; ni < 4; ni++) {
      const int row = wc + ni * 16 + c;
      const int sw  = (row & 7) << 4;
#pragma unroll
      for (int ks = 0; ks < 2; ks++)
        bfR[ni][ks] = *(const bf16x8*)(bL + row * 128 + ((ks * 64 + g * 16) ^ sw));
    }
#pragma unroll
    for (int mi = 0; mi < 4; mi++)
#pragma unroll
      for (int ni = 0; ni < 4; ni++)
#pragma unroll
        for (int ks = 0; ks < 2; ks++)
          acc[mi][ni] = __builtin_amdgcn_mfma_f32_16x16x32_bf16(
              af[mi][ks], bfR[ni][ks], acc[mi][ni], 0, 0, 0);
  }

#pragma unroll
  for (int mi = 0; mi < 4; mi++)
#pragma unroll
    for (int ni = 0; ni < 4; ni++)
#pragma unroll
      for (int r = 0; r < 4; r++) {
        const int row = rowBase + wr + mi * 16 + g * 4 + r;
        const int col = colBase + wc + ni * 16 + c;
        C[(size_t)row * NC + col] = (OutT)acc[mi][ni][r];
      }
}

// =====================================================================
// V transpose: qkv V-section [l][n][h*64+d] -> vT[(n*16+h)*64+d][l]
// =====================================================================
__global__ __launch_bounds__(256)
void transpose_v(const __bf16* __restrict__ qkv, __bf16* __restrict__ vT) {
  __shared__ char tile[64 * 160];
  const int lt = blockIdx.x;
  const int bh = blockIdx.y;
  const int n  = bh >> 4, h = bh & 15;
  const int t  = threadIdx.x;
  const int r8 = t >> 3;
  const int c8 = (t & 7) * 8;

#pragma unroll
  for (int q2 = 0; q2 < 2; q2++) {
    const int l = q2 * 32 + r8;
    const bf16x8 v = *(const bf16x8*)(qkv + (size_t)((lt * 64 + l) * 4 + n) * QKV_LD +
                                      2 * E + h * 64 + c8);
    *(bf16x8*)(tile + l * 160 + ((c8 * 2) ^ (((l >> 3) & 7) << 4))) = v;
  }
  __syncthreads();
#pragma unroll
  for (int q2 = 0; q2 < 2; q2++) {
    const int d = q2 * 32 + r8;
    bf16x8 o;
#pragma unroll
    for (int i = 0; i < 8; i++) {
      const int l = c8 + i;
      o[i] = *(const __bf16*)(tile + l * 160 + ((d * 2) ^ (((l >> 3) & 7) << 4)));
    }
    *(bf16x8*)(vT + ((size_t)bh * 64 + d) * 2048 + lt * 64 + c8) = o;
  }
}

// =====================================================================
// Causal flash attention, oversubscribed small blocks (r22, session best).
// grid (64, 32), 128 threads (2 waves): block (b, y) owns the 64-q
// supertile sup = 31-y (longest first). 2048 blocks, 16 KB LDS
// single-buffered K/V. Per-wave compute: r12-validated core (swapped
// QK^T 32x32x16, lane-local defer-max softmax, in-register P,
// PV A-frags via cndmask + __shfl_xor(32) exchange).
// =====================================================================
__global__ __launch_bounds__(128)
void attn_kernel(const __bf16* __restrict__ qkv, const __bf16* __restrict__ vT,
                 __bf16* __restrict__ out) {
  const int b   = blockIdx.x;           // 0..63 (n*16+h); XCD = b%8 L2 locality
  const int sup = 31 - (int)blockIdx.y; // 64-q supertile, longest first
  const int n   = b >> 4;
  const int h   = b & 15;

  __shared__ char kl[64 * 128];       // K tile [kv64][d64], sw2-swizzled
  __shared__ char vl[64 * 128];       // V^T tile [d64][kv64], sw2-swizzled

  const int t    = threadIdx.x;       // 0..127
  const int lane = t & 63;
  const int w    = t >> 6;            // 0..1
  const int l31  = lane & 31;
  const int hi   = lane >> 5;

  // staging: 4 chunks of 16 rows x 128B (8 thr/row); linear LDS dest,
  // pre-swizzled global source (both-sides rule)
  const int srow = t >> 3;            // 0..15
  const int scb  = (t & 7) * 16;
  int kssw[4];
#pragma unroll
  for (int q2 = 0; q2 < 4; q2++) {
    const int row = q2 * 16 + srow;
    kssw[q2] = scb ^ (((row ^ (row >> 3)) & 7) << 4);
  }

  // fragment-read rows (fixed per lane): rows l31 and 32+l31
  const int krow0 = l31,      sw0 = ((krow0 ^ (krow0 >> 3)) & 7) << 4;
  const int krow1 = 32 + l31, sw1 = ((krow1 ^ (krow1 >> 3)) & 7) << 4;

  constexpr float QSCALE = 0.125f * 1.4426950408889634f;

  const int qb_ = sup * 64 + w * 32;  // wave's q-base
  const int qg  = qb_ + l31;          // lane's global q row

  // Q as B-fragments: col q = l31, k = d = ds*16 + hi*8 + i
  bf16x8 qb[4];
  {
    const __bf16* qp = qkv + (size_t)(qg * 4 + n) * QKV_LD + h * 64;
#pragma unroll
    for (int ds = 0; ds < 4; ds++) {
      qb[ds] = *(const bf16x8*)(qp + ds * 16 + hi * 8);
#pragma unroll
      for (int i = 0; i < 8; i++) qb[ds][i] = (__bf16)((float)qb[ds][i] * QSCALE);
    }
  }

  float m_c = -3e38f, l_c = 0.f;
  f32x16 o0, o1;                      // O[q32][d32] frags, d-halves
#pragma unroll
  for (int j = 0; j < 16; j++) { o0[j] = 0.f; o1[j] = 0.f; }

  for (int kt = 0; kt <= sup; ++kt) {
    __syncthreads();                  // prior compute done -> buffers free
    // ---- stage K + V^T tile kt (single-buffered, 8 gl_lds/thread) ----
#pragma unroll
    for (int q2 = 0; q2 < 4; q2++) {
      const int kvrow = kt * 64 + q2 * 16 + srow;
      gl_lds16((const char*)(qkv + (size_t)(kvrow * 4 + n) * QKV_LD + E + h * 64) + kssw[q2],
               kl + q2 * 2048 + t * 16);
      const int vd = q2 * 16 + srow;
      gl_lds16((const char*)(vT + ((size_t)b * 64 + vd) * 2048 + kt * 64) + kssw[q2],
               vl + q2 * 2048 + t * 16);
    }
    __syncthreads();                  // staging complete (vmcnt drained)

    // ---- S^T[kv64][q32]: two 32x32 frags (kv-halves) ----
    f32x16 s0, s1;
#pragma unroll
    for (int j = 0; j < 16; j++) { s0[j] = 0.f; s1[j] = 0.f; }
    __builtin_amdgcn_s_setprio(1);
#pragma unroll
    for (int ds = 0; ds < 4; ds++) {
      const int col = ds * 32 + hi * 16;
      const bf16x8 ka0 = *(const bf16x8*)(kl + krow0 * 128 + (col ^ sw0));
      const bf16x8 ka1 = *(const bf16x8*)(kl + krow1 * 128 + (col ^ sw1));
      s0 = __builtin_amdgcn_mfma_f32_32x32x16_bf16(ka0, qb[ds], s0, 0, 0, 0);
      s1 = __builtin_amdgcn_mfma_f32_32x32x16_bf16(ka1, qb[ds], s1, 0, 0, 0);
    }
    __builtin_amdgcn_s_setprio(0);

    // ---- causal mask: diagonal tile only (kt == sup) ----
    if (kt == sup) {
#pragma unroll
      for (int reg = 0; reg < 16; reg++) {
        const int kvp = (reg & 3) + 8 * (reg >> 2) + 4 * hi;
        if (kt * 64 + kvp      > qg) s0[reg] = -1e30f;
        if (kt * 64 + 32 + kvp > qg) s1[reg] = -1e30f;
      }
    }

    // ---- lane-local online softmax (q = l31), T13 defer-max ----
    float rmax = s0[0];
#pragma unroll
    for (int reg = 1; reg < 16; reg++) rmax = fmaxf(rmax, s0[reg]);
#pragma unroll
    for (int reg = 0; reg < 16; reg++) rmax = fmaxf(rmax, s1[reg]);
    rmax = fmaxf(rmax, __shfl_xor(rmax, 32));

    if (__any(rmax > m_c + 8.f)) {
      const float mnew  = fmaxf(m_c, rmax);
      const float alpha = exp2f(m_c - mnew);
      l_c *= alpha;
#pragma unroll
      for (int reg = 0; reg < 16; reg++) {
        const int   qp = (reg & 3) + 8 * (reg >> 2) + 4 * hi;
        const float ar = __shfl(alpha, qp);
        o0[reg] *= ar;
        o1[reg] *= ar;
      }
      m_c = mnew;
    }

    float rsum = 0.f;
#pragma unroll
    for (int reg = 0; reg < 16; reg++) {
      const float e0 = exp2f(s0[reg] - m_c);
      const float e1 = exp2f(s1[reg] - m_c);
      s0[reg] = e0; s1[reg] = e1;
      rsum += e0 + e1;
    }
    rsum += __shfl_xor(rsum, 32);
    l_c += rsum;

    // ---- pack P runs: run[rg] = 4 bf16 at kv = 8*rg' + 4*hi + {0..3}
    //      (+32 for rg>=4); dwords kept split for the exchange ----
    unsigned int runA[8], runB[8];
#pragma unroll
    for (int rg = 0; rg < 8; rg++) {
      bf16x4 pk;
#pragma unroll
      for (int j = 0; j < 4; j++)
        pk[j] = (__bf16)((rg < 4) ? s0[(rg & 3) * 4 + j] : s1[(rg & 3) * 4 + j]);
      const uint2v u = *(const uint2v*)&pk;
      runA[rg] = u[0]; runB[rg] = u[1];
    }

    // ---- PV: A-frag P[q=l31][kv=16s+8hi+0..7] via hi-half exchange ----
#pragma unroll
    for (int s_ = 0; s_ < 4; s_++) {
      const unsigned int ownA = hi ? runA[2 * s_ + 1] : runA[2 * s_];
      const unsigned int ownB = hi ? runB[2 * s_ + 1] : runB[2 * s_];
      const unsigned int sndA = hi ? runA[2 * s_]     : runA[2 * s_ + 1];
      const unsigned int sndB = hi ? runB[2 * s_]     : runB[2 * s_ + 1];
      const unsigned int rxA  = (unsigned int)__shfl_xor((int)sndA, 32);
      const unsigned int rxB  = (unsigned int)__shfl_xor((int)sndB, 32);
      uint4v pu;
      pu[0] = hi ? rxA : ownA;  pu[1] = hi ? rxB : ownB;
      pu[2] = hi ? ownA : rxA;  pu[3] = hi ? ownB : rxB;
      const bf16x8 pa = *(const bf16x8*)&pu;

      const int colp = s_ * 32 + hi * 16;
      const bf16x8 vb0 = *(const bf16x8*)(vl + krow0 * 128 + (colp ^ sw0));
      const bf16x8 vb1 = *(const bf16x8*)(vl + krow1 * 128 + (colp ^ sw1));
      __builtin_amdgcn_s_setprio(1);
      o0 = __builtin_amdgcn_mfma_f32_32x32x16_bf16(pa, vb0, o0, 0, 0, 0);
      o1 = __builtin_amdgcn_mfma_f32_32x32x16_bf16(pa, vb1, o1, 0, 0, 0);
      __builtin_amdgcn_s_setprio(0);
    }
  }

  // ---- epilogue: O row q = (reg&3)+8*(reg>>2)+4*hi, col d = dh*32+l31 ----
  const float inv = 1.f / l_c;
#pragma unroll
  for (int reg = 0; reg < 16; reg++) {
    const int   qp  = (reg & 3) + 8 * (reg >> 2) + 4 * hi;
    const float li  = __shfl(inv, qp);
    const int   qrw = qb_ + qp;
    const size_t base = (size_t)(qrw * 4 + n) * E + h * 64;
    out[base + l31]      = (__bf16)(o0[reg] * li);
    out[base + 32 + l31] = (__bf16)(o1[reg] * li);
  }
}

// =====================================================================
extern "C" void kernel_launch(void* const* d_in, const int* in_sizes, int n_in,
                              void* d_out, int out_size, void* d_ws, size_t ws_size,
                              hipStream_t stream) {
  const float* x    = (const float*)d_in[0];
  const float* wqkv = (const float*)d_in[1];
  const float* wout = (const float*)d_in[2];

  char* ws = (char*)d_ws;
  __bf16* x_bf    = (__bf16*)ws;                         ws += (size_t)M * E * 2;       // 16 MB
  __bf16* wqkv_bf = (__bf16*)ws;                         ws += (size_t)QKV_LD * E * 2;  //  6 MB
  __bf16* wout_bf = (__bf16*)ws;                         ws += (size_t)E * E * 2;       //  2 MB
  __bf16* qkv     = (__bf16*)ws;                         ws += (size_t)M * QKV_LD * 2;  // 48 MB
  __bf16* attno   = (__bf16*)ws;                                                        // 16 MB
  __bf16* vT      = x_bf;   // x_bf dead after QKV GEMM; reuse as vT (16 MB)
  float*  outp    = (float*)d_out;

  cvt_all<<<12288, 256, 0, stream>>>(x, wqkv, wout, x_bf, wqkv_bf, wout_bf);

  gemm_bt<QKV_LD, __bf16><<<dim3(QKV_LD / 128, M / 128), 256, 0, stream>>>(x_bf, wqkv_bf, qkv);
  transpose_v<<<dim3(L / 64, NB * H), 256, 0, stream>>>(qkv, vT);
  attn_kernel<<<dim3(NB * H, 32), 128, 0, stream>>>(qkv, vT, attno);
  gemm_bt<E, float><<<dim3(E / 128, M / 128), 256, 0, stream>>>(attno, wout_bf, outp);
}